// Round 3
// baseline (548.079 us; speedup 1.0000x reference)
//
#include <hip/hip_runtime.h>

#define NC 24  // N*C = 8*3

typedef float f32x4 __attribute__((ext_vector_type(4)));

// ---------- scalar pyrDown point: 5x5 binomial, reflect-101 ----------
__device__ __forceinline__ float pyr_point(const float* __restrict__ ip,
                                           int Hi, int Wi, int oy, int ox)
{
    const float k1[5] = {0.0625f, 0.25f, 0.375f, 0.25f, 0.0625f};
    float acc = 0.f;
#pragma unroll
    for (int i = 0; i < 5; ++i) {
        int y = 2 * oy - 2 + i;
        y = (y < 0) ? -y : y;
        y = (y >= Hi) ? (2 * Hi - 2 - y) : y;
        const float* rp = ip + (size_t)y * Wi;
        float r = 0.f;
#pragma unroll
        for (int j = 0; j < 5; ++j) {
            int xx = 2 * ox - 2 + j;
            xx = (xx < 0) ? -xx : xx;
            xx = (xx >= Wi) ? (2 * Wi - 2 - xx) : xx;
            r = fmaf(k1[j], rp[xx], r);
        }
        acc = fmaf(k1[i], r, acc);
    }
    return acc;
}

// ---------- Gaussian blur point, reflect-101 ----------
template <int K>
__device__ __forceinline__ float blur_point(const float* __restrict__ ip,
                                            int H, int W, int oy, int ox,
                                            const float* __restrict__ w)
{
    const int R = K / 2;
    float acc = 0.f;
#pragma unroll
    for (int i = 0; i < K; ++i) {
        int y = oy - R + i;
        y = (y < 0) ? -y : y;
        y = (y >= H) ? (2 * H - 2 - y) : y;
        const float* rp = ip + (size_t)y * W;
        float r = 0.f;
#pragma unroll
        for (int j = 0; j < K; ++j) {
            int xx = ox - R + j;
            xx = (xx < 0) ? -xx : xx;
            xx = (xx >= W) ? (2 * W - 2 - xx) : xx;
            r = fmaf(w[j], rp[xx], r);
        }
        acc = fmaf(w[i], r, acc);
    }
    return acc;
}

// ---------- 2x bilinear (half-pixel, edge clamp) single point ----------
__device__ __forceinline__ float up2_point(const float* __restrict__ ip,
                                           int Hi, int Wi, int oy, int ox)
{
    int my = oy >> 1, py = oy & 1;
    int mx = ox >> 1, px = ox & 1;
    int ya = py ? my : (my > 0 ? my - 1 : 0);
    int yb = py ? (my + 1 < Hi ? my + 1 : Hi - 1) : my;
    float wya = py ? 0.75f : 0.25f;
    float wyb = py ? 0.25f : 0.75f;
    int xa = px ? mx : (mx > 0 ? mx - 1 : 0);
    int xb = px ? (mx + 1 < Wi ? mx + 1 : Wi - 1) : mx;
    float wxa = px ? 0.75f : 0.25f;
    float wxb = px ? 0.25f : 0.75f;
    return wya * (wxa * ip[(size_t)ya * Wi + xa] + wxb * ip[(size_t)ya * Wi + xb]) +
           wyb * (wxa * ip[(size_t)yb * Wi + xa] + wxb * ip[(size_t)yb * Wi + xb]);
}

// ---------- pyrDown, 4 outputs/thread, float4 interior fast path ----------
__global__ void __launch_bounds__(256) pyrdown4_kernel(
    const float* __restrict__ in, float* __restrict__ out,
    int Hi, int Wi, int Ho, int Wo, float scale, float offs)
{
    int qx = blockIdx.x * blockDim.x + threadIdx.x;  // output quad index
    int oy = blockIdx.y * blockDim.y + threadIdx.y;
    int nc = blockIdx.z;
    int ox0 = qx * 4;
    if (ox0 >= Wo || oy >= Ho) return;
    const float* ip = in + (size_t)nc * Hi * Wi;
    const float k[5] = {0.0625f, 0.25f, 0.375f, 0.25f, 0.0625f};

    bool fastx = (qx >= 1) && (8 * qx + 11 <= Wi - 1) && (ox0 + 3 < Wo);
    bool fasty = (oy >= 1) && (2 * oy + 2 <= Hi - 1);
    if (fastx && fasty) {
        int x0 = 8 * qx - 4;  // float4-aligned base; needed cols are rel [2,12]
        float col[11];
#pragma unroll
        for (int j = 0; j < 11; ++j) col[j] = 0.f;
        const float* rp = ip + (size_t)(2 * oy - 2) * Wi + x0;
#pragma unroll
        for (int i = 0; i < 5; ++i) {
            f32x4 a = *(const f32x4*)(rp);
            f32x4 b = *(const f32x4*)(rp + 4);
            f32x4 c4 = *(const f32x4*)(rp + 8);
            f32x4 d = *(const f32x4*)(rp + 12);
            float rv[16] = {a[0], a[1], a[2], a[3], b[0], b[1], b[2], b[3],
                            c4[0], c4[1], c4[2], c4[3], d[0], d[1], d[2], d[3]};
#pragma unroll
            for (int j = 0; j < 11; ++j) col[j] = fmaf(k[i], rv[j + 2], col[j]);
            rp += Wi;
        }
        f32x4 o;
#pragma unroll
        for (int p = 0; p < 4; ++p) {
            float s = 0.f;
#pragma unroll
            for (int j = 0; j < 5; ++j) s = fmaf(k[j], col[2 * p + j], s);
            o[p] = fmaf(s, scale, offs);
        }
        *(f32x4*)&out[((size_t)nc * Ho + oy) * Wo + ox0] = o;
    } else {
#pragma unroll
        for (int p = 0; p < 4; ++p) {
            int ox = ox0 + p;
            if (ox < Wo)
                out[((size_t)nc * Ho + oy) * Wo + ox] =
                    fmaf(pyr_point(ip, Hi, Wi, oy, ox), scale, offs);
        }
    }
}

// ---------- fused tail: levels <=160, one block per nc ----------
struct TailPtrs {
    float *L2, *L3, *L4, *L5, *L6, *L7, *L8;
    float *b30, *b150, *b300;
    float *u300_10, *u150_20, *u300_20, *u150_40, *u300_40;
    float *u30_80, *u150_80, *u300_80;
    float *u30_160, *u150_160, *u300_160;
};

__global__ void __launch_bounds__(1024) tail_kernel(TailPtrs P)
{
    const int nc = blockIdx.x;
    const int tid = threadIdx.x;
    auto at = [&](float* p, int d) { return p + (size_t)nc * d * d; };
    const float* L2 = at(P.L2, 320);
    float *L3 = at(P.L3, 160), *L4 = at(P.L4, 80), *L5 = at(P.L5, 40);
    float *L6 = at(P.L6, 20), *L7 = at(P.L7, 10), *L8 = at(P.L8, 5);
    float *b30 = at(P.b30, 40), *b150 = at(P.b150, 10), *b300 = at(P.b300, 5);
    float *u300_10 = at(P.u300_10, 10);
    float *u150_20 = at(P.u150_20, 20), *u300_20 = at(P.u300_20, 20);
    float *u150_40 = at(P.u150_40, 40), *u300_40 = at(P.u300_40, 40);
    float *u30_80 = at(P.u30_80, 80), *u150_80 = at(P.u150_80, 80), *u300_80 = at(P.u300_80, 80);
    float *u30_160 = at(P.u30_160, 160), *u150_160 = at(P.u150_160, 160), *u300_160 = at(P.u300_160, 160);

    // Gaussian weights (uniform across threads; cheap)
    float w7[7], w9[9];
    {
        float s = 1.4f, s2 = 2.f * s * s, sum = 0.f;
#pragma unroll
        for (int i = 0; i < 7; ++i) { float d = (float)i - 3.f; w7[i] = expf(-(d * d) / s2); sum += w7[i]; }
#pragma unroll
        for (int i = 0; i < 7; ++i) w7[i] /= sum;
        s = 1.7f; s2 = 2.f * s * s; sum = 0.f;
#pragma unroll
        for (int i = 0; i < 9; ++i) { float d = (float)i - 4.f; w9[i] = expf(-(d * d) / s2); sum += w9[i]; }
#pragma unroll
        for (int i = 0; i < 9; ++i) w9[i] /= sum;
    }

    auto pd = [&](const float* in, float* out, int Hi) {
        int Ho = Hi >> 1, n = Ho * Ho;
        for (int i = tid; i < n; i += 1024) {
            int oy = i / Ho, ox = i - oy * Ho;
            out[i] = pyr_point(in, Hi, Hi, oy, ox);
        }
        __syncthreads();
    };
    auto up = [&](const float* in, float* out, int Hi) {
        int Ho = Hi << 1, n = Ho * Ho;
        for (int i = tid; i < n; i += 1024) {
            int oy = i / Ho, ox = i - oy * Ho;
            out[i] = up2_point(in, Hi, Hi, oy, ox);
        }
    };

    // down chain
    pd(L2, L3, 320);
    pd(L3, L4, 160);
    pd(L4, L5, 80);
    pd(L5, L6, 40);
    pd(L6, L7, 20);
    pd(L7, L8, 10);
    // blurs (all inputs ready; independent)
    for (int i = tid; i < 40 * 40; i += 1024) {
        int oy = i / 40, ox = i - oy * 40;
        b30[i] = blur_point<7>(L5, 40, 40, oy, ox, w7);
    }
    for (int i = tid; i < 10 * 10; i += 1024) {
        int oy = i / 10, ox = i - oy * 10;
        b150[i] = blur_point<9>(L7, 10, 10, oy, ox, w9);
    }
    for (int i = tid; i < 5 * 5; i += 1024) {
        int oy = i / 5, ox = i - oy * 5;
        b300[i] = blur_point<9>(L8, 5, 5, oy, ox, w9);
    }
    __syncthreads();
    // up chains
    up(b300, u300_10, 5);
    __syncthreads();
    up(b150, u150_20, 10); up(u300_10, u300_20, 10);
    __syncthreads();
    up(u150_20, u150_40, 20); up(u300_20, u300_40, 20);
    __syncthreads();
    up(b30, u30_80, 40); up(u150_40, u150_80, 40); up(u300_40, u300_80, 40);
    __syncthreads();
    up(u30_80, u30_160, 80); up(u150_80, u150_160, 80); up(u300_80, u300_160, 80);
}

// ---------- 2x bilinear upsample, batched 3 tensors ----------
__global__ void up2_kernel(const float* __restrict__ i0, const float* __restrict__ i1,
                           const float* __restrict__ i2,
                           float* __restrict__ o0, float* __restrict__ o1, float* __restrict__ o2,
                           int Hi, int Wi)
{
    int ox = blockIdx.x * blockDim.x + threadIdx.x;
    int oy = blockIdx.y * blockDim.y + threadIdx.y;
    int z = blockIdx.z;           // t * NC + nc
    int t = z / NC, nc = z - t * NC;
    int Ho = 2 * Hi, Wo = 2 * Wi;
    if (ox >= Wo || oy >= Ho) return;
    const float* in = (t == 0) ? i0 : (t == 1) ? i1 : i2;
    float* out = (t == 0) ? o0 : (t == 1) ? o1 : o2;
    out[((size_t)nc * Ho + oy) * Wo + ox] =
        up2_point(in + (size_t)nc * Hi * Wi, Hi, Wi, oy, ox);
}

// ---------- final: 4x4 block per thread, fused 4x upsample + MSR ----------
__global__ void __launch_bounds__(256) final_kernel(
    const float* __restrict__ x,
    const float* __restrict__ f30,
    const float* __restrict__ f150,
    const float* __restrict__ f300,
    float* __restrict__ out)
{
    const int H = 1280, W = 1280, Hs = 320, Ws = 320;
    int t = blockIdx.x * 256 + threadIdx.x;          // over 8 * 320 * 320 blocks
    if (t >= 8 * Hs * Ws) return;
    int n = t / (Hs * Ws);
    int r = t - n * (Hs * Ws);
    int by = r / Ws;
    int bx = r - by * Ws;

    int ry[3], rx[3];
    ry[0] = by > 0 ? by - 1 : 0; ry[1] = by; ry[2] = by < Hs - 1 ? by + 1 : Hs - 1;
    rx[0] = bx > 0 ? bx - 1 : 0; rx[1] = bx; rx[2] = bx < Ws - 1 ? bx + 1 : Ws - 1;
    const float WP[4][3] = {{0.375f, 0.625f, 0.f},
                            {0.1875f, 0.75f, 0.0625f},
                            {0.0625f, 0.75f, 0.1875f},
                            {0.f, 0.625f, 0.375f}};

    // load x: 3 channels x 4 rows of float4 (nontemporal: read-once stream)
    f32x4 xi[3][4];
#pragma unroll
    for (int c = 0; c < 3; ++c)
#pragma unroll
        for (int qy = 0; qy < 4; ++qy)
            xi[c][qy] = __builtin_nontemporal_load(
                (const f32x4*)&x[((size_t)(n * 3 + c) * H + 4 * by + qy) * W + 4 * bx]);

    float crcp[4][4];
#pragma unroll
    for (int qy = 0; qy < 4; ++qy)
#pragma unroll
        for (int qx = 0; qx < 4; ++qx) {
            float s = (xi[0][qy][qx] + xi[1][qy][qx] + xi[2][qy][qx]) * 255.f + 3.f;
            crcp[qy][qx] = __fdividef(2.f, s + 1e-6f);
        }

    const float* F[3] = {f30, f150, f300};
#pragma unroll
    for (int c = 0; c < 3; ++c) {
        float prod[4][4];
#pragma unroll
        for (int qy = 0; qy < 4; ++qy)
#pragma unroll
            for (int qx = 0; qx < 4; ++qx) prod[qy][qx] = 1.f;

#pragma unroll
        for (int s = 0; s < 3; ++s) {
            const float* fp = F[s] + (size_t)(n * 3 + c) * Hs * Ws;
            float v[3][3];
#pragma unroll
            for (int i = 0; i < 3; ++i)
#pragma unroll
                for (int j = 0; j < 3; ++j) v[i][j] = fp[(size_t)ry[i] * Ws + rx[j]];
#pragma unroll
            for (int qy = 0; qy < 4; ++qy) {
                float vy0 = WP[qy][0] * v[0][0] + WP[qy][1] * v[1][0] + WP[qy][2] * v[2][0];
                float vy1 = WP[qy][0] * v[0][1] + WP[qy][1] * v[1][1] + WP[qy][2] * v[2][1];
                float vy2 = WP[qy][0] * v[0][2] + WP[qy][1] * v[1][2] + WP[qy][2] * v[2][2];
#pragma unroll
                for (int qx = 0; qx < 4; ++qx) {
                    float val = WP[qx][0] * vy0 + WP[qx][1] * vy1 + WP[qx][2] * vy2;
                    prod[qy][qx] *= (val + 1e-6f);
                }
            }
        }

#pragma unroll
        for (int qy = 0; qy < 4; ++qy) {
            f32x4 o;
#pragma unroll
            for (int qx = 0; qx < 4; ++qx) {
                float img = xi[c][qy][qx] * 255.f + 1.f;
                float a = img + 1e-6f;
                float l2a = __log2f(__fdividef(a * a * a, prod[qy][qx]));
                float carg = fmaf(img, crcp[qy][qx], 1.f);
                float l2c = __log2f(carg);
                float e = fmaf(l2a * l2c, 81.55715246f, 128.f);
                e = fminf(fmaxf(e, 0.f), 255.f);
                o[qx] = e * (1.f / 255.f);
            }
            __builtin_nontemporal_store(
                o, (f32x4*)&out[((size_t)(n * 3 + c) * H + 4 * by + qy) * W + 4 * bx]);
        }
    }
}

extern "C" void kernel_launch(void* const* d_in, const int* in_sizes, int n_in,
                              void* d_out, int out_size, void* d_ws, size_t ws_size,
                              hipStream_t stream)
{
    const float* x = (const float*)d_in[0];
    float* out = (float*)d_out;
    float* ws = (float*)d_ws;

    size_t off = 0;
    auto alloc = [&](int d) { float* p = ws + off; off += (size_t)NC * d * d; return p; };
    float* L1 = alloc(640);
    TailPtrs P;
    P.L2 = alloc(320);
    P.L3 = alloc(160); P.L4 = alloc(80); P.L5 = alloc(40);
    P.L6 = alloc(20);  P.L7 = alloc(10); P.L8 = alloc(5);
    P.b30 = alloc(40); P.b150 = alloc(10); P.b300 = alloc(5);
    P.u300_10 = alloc(10);
    P.u150_20 = alloc(20); P.u300_20 = alloc(20);
    P.u150_40 = alloc(40); P.u300_40 = alloc(40);
    P.u30_80 = alloc(80); P.u150_80 = alloc(80); P.u300_80 = alloc(80);
    P.u30_160 = alloc(160); P.u150_160 = alloc(160); P.u300_160 = alloc(160);
    float* u30_320 = alloc(320);
    float* u150_320 = alloc(320);
    float* u300_320 = alloc(320);
    (void)ws_size; (void)in_sizes; (void)n_in; (void)out_size;

    dim3 blk(32, 8, 1);
    auto grid2 = [&](int Wo, int Ho, int z) { return dim3((Wo + 31) / 32, (Ho + 7) / 8, z); };
    auto grid4 = [&](int Wo, int Ho) { return dim3((Wo / 4 + 31) / 32, (Ho + 7) / 8, NC); };

    // big pyramid levels
    pyrdown4_kernel<<<grid4(640, 640), blk, 0, stream>>>(x,  L1,   1280, 1280, 640, 640, 255.f, 1.f);
    pyrdown4_kernel<<<grid4(320, 320), blk, 0, stream>>>(L1, P.L2, 640,  640,  320, 320, 1.f, 0.f);
    // fused small tail (levels <=160): downs, blurs, ups back to 160
    tail_kernel<<<dim3(NC, 1, 1), dim3(1024, 1, 1), 0, stream>>>(P);
    // batched up 160 -> 320 for all three sigmas
    up2_kernel<<<grid2(320, 320, 3 * NC), blk, 0, stream>>>(
        P.u30_160, P.u150_160, P.u300_160, u30_320, u150_320, u300_320, 160, 160);
    // fused final
    final_kernel<<<dim3(3200, 1, 1), dim3(256, 1, 1), 0, stream>>>(x, u30_320, u150_320, u300_320, out);
}

// Round 4
// 420.480 us; speedup vs baseline: 1.3035x; 1.3035x over previous
//
#include <hip/hip_runtime.h>

#define NC 24  // N*C = 8*3

typedef float f32x4 __attribute__((ext_vector_type(4)));

// ---------- scalar pyrDown point: 5x5 binomial, reflect-101 ----------
__device__ __forceinline__ float pyr_point(const float* ip, int Hi, int Wi, int oy, int ox)
{
    const float k1[5] = {0.0625f, 0.25f, 0.375f, 0.25f, 0.0625f};
    float acc = 0.f;
#pragma unroll
    for (int i = 0; i < 5; ++i) {
        int y = 2 * oy - 2 + i;
        y = (y < 0) ? -y : y;
        y = (y >= Hi) ? (2 * Hi - 2 - y) : y;
        const float* rp = ip + (size_t)y * Wi;
        float r = 0.f;
#pragma unroll
        for (int j = 0; j < 5; ++j) {
            int xx = 2 * ox - 2 + j;
            xx = (xx < 0) ? -xx : xx;
            xx = (xx >= Wi) ? (2 * Wi - 2 - xx) : xx;
            r = fmaf(k1[j], rp[xx], r);
        }
        acc = fmaf(k1[i], r, acc);
    }
    return acc;
}

// ---------- Gaussian blur point, reflect-101 ----------
template <int K>
__device__ __forceinline__ float blur_point(const float* ip, int H, int W, int oy, int ox,
                                            const float* w)
{
    const int R = K / 2;
    float acc = 0.f;
#pragma unroll
    for (int i = 0; i < K; ++i) {
        int y = oy - R + i;
        y = (y < 0) ? -y : y;
        y = (y >= H) ? (2 * H - 2 - y) : y;
        const float* rp = ip + (size_t)y * W;
        float r = 0.f;
#pragma unroll
        for (int j = 0; j < K; ++j) {
            int xx = ox - R + j;
            xx = (xx < 0) ? -xx : xx;
            xx = (xx >= W) ? (2 * W - 2 - xx) : xx;
            r = fmaf(w[j], rp[xx], r);
        }
        acc = fmaf(w[i], r, acc);
    }
    return acc;
}

// ---------- pyrDown, 4 outputs/thread, float4 interior fast path ----------
__global__ void __launch_bounds__(256) pyrdown4_kernel(
    const float* __restrict__ in, float* __restrict__ out,
    int Hi, int Wi, int Ho, int Wo, float scale, float offs)
{
    int qx = blockIdx.x * blockDim.x + threadIdx.x;  // output quad index
    int oy = blockIdx.y * blockDim.y + threadIdx.y;
    int nc = blockIdx.z;
    int ox0 = qx * 4;
    if (ox0 >= Wo || oy >= Ho) return;
    const float* ip = in + (size_t)nc * Hi * Wi;
    const float k[5] = {0.0625f, 0.25f, 0.375f, 0.25f, 0.0625f};

    bool fastx = (qx >= 1) && (8 * qx + 11 <= Wi - 1) && (ox0 + 3 < Wo);
    bool fasty = (oy >= 1) && (2 * oy + 2 <= Hi - 1);
    if (fastx && fasty) {
        int x0 = 8 * qx - 4;  // float4-aligned base; needed cols are rel [2,12]
        float col[11];
#pragma unroll
        for (int j = 0; j < 11; ++j) col[j] = 0.f;
        const float* rp = ip + (size_t)(2 * oy - 2) * Wi + x0;
#pragma unroll
        for (int i = 0; i < 5; ++i) {
            f32x4 a = *(const f32x4*)(rp);
            f32x4 b = *(const f32x4*)(rp + 4);
            f32x4 c4 = *(const f32x4*)(rp + 8);
            f32x4 d = *(const f32x4*)(rp + 12);
            float rv[16] = {a[0], a[1], a[2], a[3], b[0], b[1], b[2], b[3],
                            c4[0], c4[1], c4[2], c4[3], d[0], d[1], d[2], d[3]};
#pragma unroll
            for (int j = 0; j < 11; ++j) col[j] = fmaf(k[i], rv[j + 2], col[j]);
            rp += Wi;
        }
        f32x4 o;
#pragma unroll
        for (int p = 0; p < 4; ++p) {
            float s = 0.f;
#pragma unroll
            for (int j = 0; j < 5; ++j) s = fmaf(k[j], col[2 * p + j], s);
            o[p] = fmaf(s, scale, offs);
        }
        *(f32x4*)&out[((size_t)nc * Ho + oy) * Wo + ox0] = o;
    } else {
#pragma unroll
        for (int p = 0; p < 4; ++p) {
            int ox = ox0 + p;
            if (ox < Wo)
                out[((size_t)nc * Ho + oy) * Wo + ox] =
                    fmaf(pyr_point(ip, Hi, Wi, oy, ox), scale, offs);
        }
    }
}

// ---------- base_kernel: 80 -> {40,20,10,5} + blurs, all in LDS, 1 block/nc ----------
__global__ void __launch_bounds__(256) base_kernel(
    const float* __restrict__ L4g, float* __restrict__ b30g,
    float* __restrict__ b150g, float* __restrict__ b300g)
{
    __shared__ float sL4[80 * 80];
    __shared__ float sL5[40 * 40];
    __shared__ float sL6[20 * 20];
    __shared__ float sL7[10 * 10];
    __shared__ float sL8[5 * 5];
    const int nc = blockIdx.x;
    const int tid = threadIdx.x;

    float w7[7], w9[9];
    {
        float s = 1.4f, s2 = 2.f * s * s, sum = 0.f;
#pragma unroll
        for (int i = 0; i < 7; ++i) { float d = (float)i - 3.f; w7[i] = expf(-(d * d) / s2); sum += w7[i]; }
#pragma unroll
        for (int i = 0; i < 7; ++i) w7[i] /= sum;
        s = 1.7f; s2 = 2.f * s * s; sum = 0.f;
#pragma unroll
        for (int i = 0; i < 9; ++i) { float d = (float)i - 4.f; w9[i] = expf(-(d * d) / s2); sum += w9[i]; }
#pragma unroll
        for (int i = 0; i < 9; ++i) w9[i] /= sum;
    }

    // coalesced load of L4 (80x80) into LDS
    const float* src = L4g + (size_t)nc * 6400;
    for (int i = tid; i < 1600; i += 256)
        *(f32x4*)&sL4[4 * i] = *(const f32x4*)&src[4 * i];
    __syncthreads();
    for (int i = tid; i < 1600; i += 256) {
        int oy = i / 40, ox = i - oy * 40;
        sL5[i] = pyr_point(sL4, 80, 80, oy, ox);
    }
    __syncthreads();
    for (int i = tid; i < 400; i += 256) {
        int oy = i / 20, ox = i - oy * 20;
        sL6[i] = pyr_point(sL5, 40, 40, oy, ox);
    }
    __syncthreads();
    for (int i = tid; i < 100; i += 256) {
        int oy = i / 10, ox = i - oy * 10;
        sL7[i] = pyr_point(sL6, 20, 20, oy, ox);
    }
    __syncthreads();
    for (int i = tid; i < 25; i += 256) {
        int oy = i / 5, ox = i - oy * 5;
        sL8[i] = pyr_point(sL7, 10, 10, oy, ox);
    }
    __syncthreads();
    for (int i = tid; i < 1600; i += 256) {
        int oy = i / 40, ox = i - oy * 40;
        b30g[(size_t)nc * 1600 + i] = blur_point<7>(sL5, 40, 40, oy, ox, w7);
    }
    for (int i = tid; i < 100; i += 256) {
        int oy = i / 10, ox = i - oy * 10;
        b150g[(size_t)nc * 100 + i] = blur_point<9>(sL7, 10, 10, oy, ox, w9);
    }
    for (int i = tid; i < 25; i += 256) {
        int oy = i / 5, ox = i - oy * 5;
        b300g[(size_t)nc * 25 + i] = blur_point<9>(sL8, 5, 5, oy, ox, w9);
    }
}

// ---------- mega_final: per 64x64 tile, rebuild 9 up-chains in LDS + MSR ----------
// LDS plane offsets (floats), per channel stride 1963:
//   sigma30 : l3(base40)=0, l2=49, l1=130, l0=274        (caps 7,9,12,18)
//   sigma150: l5(base10)=598, l4=634, l3=670, l2=719, l1=800, l0=944
//   sigma300: l6(base5)=1268, l5=1293, l4=1329, l3=1365, l2=1414, l1=1495, l0=1639
__global__ void __launch_bounds__(256) mega_final(
    const float* __restrict__ x,
    const float* __restrict__ b30g,
    const float* __restrict__ b150g,
    const float* __restrict__ b300g,
    float* __restrict__ out)
{
    const int H = 1280, W = 1280;
    __shared__ float S[3 * 1963];

    const int tid = threadIdx.x;
    const int X0 = blockIdx.x * 64, Y0 = blockIdx.y * 64;
    const int n = blockIdx.z;

    // per-level needed ranges (same for all chains); l: 0=320,1=160,2=80,3=40,4=20,5=10,6=5
    const int LS[7] = {320, 160, 80, 40, 20, 10, 5};
    int ay[7], by[7], ax[7], bx[7];
    ay[0] = max(0, Y0 / 4 - 1); by[0] = min(319, Y0 / 4 + 16);
    ax[0] = max(0, X0 / 4 - 1); bx[0] = min(319, X0 / 4 + 16);
#pragma unroll
    for (int l = 1; l < 7; ++l) {
        ay[l] = max(0, (ay[l - 1] >> 1) - 1); by[l] = min(LS[l] - 1, (by[l - 1] >> 1) + 1);
        ax[l] = max(0, (ax[l - 1] >> 1) - 1); bx[l] = min(LS[l] - 1, (bx[l - 1] >> 1) + 1);
    }
    const int o300t[7] = {1639, 1495, 1414, 1365, 1329, 1293, 1268};
    const int o150t[6] = {944, 800, 719, 670, 634, 598};
    const int o30t[4]  = {274, 130, 49, 0};

    // ---- stage 0: load base patches ----
    {
        int ny = by[3] - ay[3] + 1, nx = bx[3] - ax[3] + 1;  // b30 at l3
        for (int i = tid; i < 3 * ny * nx; i += 256) {
            int c = i / (ny * nx), pt = i - c * (ny * nx);
            int ry = pt / nx, rx = pt - ry * nx;
            S[c * 1963 + o30t[3] + pt] =
                b30g[(size_t)(n * 3 + c) * 1600 + (ay[3] + ry) * 40 + ax[3] + rx];
        }
        ny = by[5] - ay[5] + 1; nx = bx[5] - ax[5] + 1;      // b150 at l5
        for (int i = tid; i < 3 * ny * nx; i += 256) {
            int c = i / (ny * nx), pt = i - c * (ny * nx);
            int ry = pt / nx, rx = pt - ry * nx;
            S[c * 1963 + o150t[5] + pt] =
                b150g[(size_t)(n * 3 + c) * 100 + (ay[5] + ry) * 10 + ax[5] + rx];
        }
        ny = by[6] - ay[6] + 1; nx = bx[6] - ax[6] + 1;      // b300 at l6
        for (int i = tid; i < 3 * ny * nx; i += 256) {
            int c = i / (ny * nx), pt = i - c * (ny * nx);
            int ry = pt / nx, rx = pt - ry * nx;
            S[c * 1963 + o300t[6] + pt] =
                b300g[(size_t)(n * 3 + c) * 25 + (ay[6] + ry) * 5 + ax[6] + rx];
        }
    }
    __syncthreads();

    // ---- up ladder: l = 5..0 (dst level l, src level l+1) ----
#pragma unroll
    for (int l = 5; l >= 0; --l) {
        int srcO[9], dstO[9];
        int m = 0;
#pragma unroll
        for (int c = 0; c < 3; ++c) { srcO[m] = c * 1963 + o300t[l + 1]; dstO[m] = c * 1963 + o300t[l]; ++m; }
        if (l <= 4) {
#pragma unroll
            for (int c = 0; c < 3; ++c) { srcO[m] = c * 1963 + o150t[l + 1]; dstO[m] = c * 1963 + o150t[l]; ++m; }
        }
        if (l <= 2) {
#pragma unroll
            for (int c = 0; c < 3; ++c) { srcO[m] = c * 1963 + o30t[l + 1]; dstO[m] = c * 1963 + o30t[l]; ++m; }
        }
        int ny = by[l] - ay[l] + 1, nx = bx[l] - ax[l] + 1;
        int nxS = bx[l + 1] - ax[l + 1] + 1;
        int Ssrc = LS[l + 1];
        int npts = ny * nx;
        for (int i = tid; i < m * npts; i += 256) {
            int p = i / npts, pt = i - p * npts;
            int ry = pt / nx, rx = pt - ry * nx;
            int oy = ay[l] + ry, ox = ax[l] + rx;
            int my = oy >> 1, py = oy & 1;
            int mx = ox >> 1, px = ox & 1;
            int yA = py ? my : max(my - 1, 0);
            int yB = py ? min(my + 1, Ssrc - 1) : my;
            float wyA = py ? 0.75f : 0.25f, wyB = py ? 0.25f : 0.75f;
            int xA = px ? mx : max(mx - 1, 0);
            int xB = px ? min(mx + 1, Ssrc - 1) : mx;
            float wxA = px ? 0.75f : 0.25f, wxB = px ? 0.25f : 0.75f;
            const float* sp = &S[srcO[p]];
            int la = (yA - ay[l + 1]) * nxS - ax[l + 1];
            int lb = (yB - ay[l + 1]) * nxS - ax[l + 1];
            float v = wyA * (wxA * sp[la + xA] + wxB * sp[la + xB]) +
                      wyB * (wxA * sp[lb + xA] + wxB * sp[lb + xB]);
            S[dstO[p] + pt] = v;
        }
        __syncthreads();
    }

    // ---- MSR per thread: 4x4 px block, 3 channels ----
    int tyi = tid >> 4, txi = tid & 15;
    int byi = Y0 / 4 + tyi, bxi = X0 / 4 + txi;   // global 320-level index
    int nx0 = bx[0] - ax[0] + 1;
    int ry[3], rx[3];
    ry[0] = (byi > 0 ? byi - 1 : 0) - ay[0]; ry[1] = byi - ay[0];
    ry[2] = (byi < 319 ? byi + 1 : 319) - ay[0];
    rx[0] = (bxi > 0 ? bxi - 1 : 0) - ax[0]; rx[1] = bxi - ax[0];
    rx[2] = (bxi < 319 ? bxi + 1 : 319) - ax[0];
    const float WP[4][3] = {{0.375f, 0.625f, 0.f},
                            {0.1875f, 0.75f, 0.0625f},
                            {0.0625f, 0.75f, 0.1875f},
                            {0.f, 0.625f, 0.375f}};
    const int ol0[3] = {274, 944, 1639};  // sigma30/150/300 at l0

    f32x4 xi[3][4];
#pragma unroll
    for (int c = 0; c < 3; ++c)
#pragma unroll
        for (int qy = 0; qy < 4; ++qy)
            xi[c][qy] = __builtin_nontemporal_load(
                (const f32x4*)&x[((size_t)(n * 3 + c) * H + 4 * byi + qy) * W + 4 * bxi]);

    float crcp[4][4];
#pragma unroll
    for (int qy = 0; qy < 4; ++qy)
#pragma unroll
        for (int qx = 0; qx < 4; ++qx) {
            float s = (xi[0][qy][qx] + xi[1][qy][qx] + xi[2][qy][qx]) * 255.f + 3.f;
            crcp[qy][qx] = __fdividef(2.f, s + 1e-6f);
        }

#pragma unroll
    for (int c = 0; c < 3; ++c) {
        float prod[4][4];
#pragma unroll
        for (int qy = 0; qy < 4; ++qy)
#pragma unroll
            for (int qx = 0; qx < 4; ++qx) prod[qy][qx] = 1.f;

#pragma unroll
        for (int s = 0; s < 3; ++s) {
            const float* fp = &S[c * 1963 + ol0[s]];
            float v[3][3];
#pragma unroll
            for (int i = 0; i < 3; ++i)
#pragma unroll
                for (int j = 0; j < 3; ++j) v[i][j] = fp[ry[i] * nx0 + rx[j]];
#pragma unroll
            for (int qy = 0; qy < 4; ++qy) {
                float vy0 = WP[qy][0] * v[0][0] + WP[qy][1] * v[1][0] + WP[qy][2] * v[2][0];
                float vy1 = WP[qy][0] * v[0][1] + WP[qy][1] * v[1][1] + WP[qy][2] * v[2][1];
                float vy2 = WP[qy][0] * v[0][2] + WP[qy][1] * v[1][2] + WP[qy][2] * v[2][2];
#pragma unroll
                for (int qx = 0; qx < 4; ++qx) {
                    float val = WP[qx][0] * vy0 + WP[qx][1] * vy1 + WP[qx][2] * vy2;
                    prod[qy][qx] *= (val + 1e-6f);
                }
            }
        }

#pragma unroll
        for (int qy = 0; qy < 4; ++qy) {
            f32x4 o;
#pragma unroll
            for (int qx = 0; qx < 4; ++qx) {
                float img = xi[c][qy][qx] * 255.f + 1.f;
                float a = img + 1e-6f;
                float l2a = __log2f(__fdividef(a * a * a, prod[qy][qx]));
                float carg = fmaf(img, crcp[qy][qx], 1.f);
                float l2c = __log2f(carg);
                float e = fmaf(l2a * l2c, 81.55715246f, 128.f);
                e = fminf(fmaxf(e, 0.f), 255.f);
                o[qx] = e * (1.f / 255.f);
            }
            __builtin_nontemporal_store(
                o, (f32x4*)&out[((size_t)(n * 3 + c) * H + 4 * byi + qy) * W + 4 * bxi]);
        }
    }
}

extern "C" void kernel_launch(void* const* d_in, const int* in_sizes, int n_in,
                              void* d_out, int out_size, void* d_ws, size_t ws_size,
                              hipStream_t stream)
{
    const float* x = (const float*)d_in[0];
    float* out = (float*)d_out;
    float* ws = (float*)d_ws;

    size_t off = 0;
    auto alloc = [&](int d) { float* p = ws + off; off += (size_t)NC * d * d; return p; };
    float* L1 = alloc(640);
    float* L2 = alloc(320);
    float* L3 = alloc(160);
    float* L4 = alloc(80);
    float* b30 = alloc(40);
    float* b150 = alloc(10);
    float* b300 = alloc(5);
    (void)ws_size; (void)in_sizes; (void)n_in; (void)out_size;

    dim3 blk(32, 8, 1);
    auto grid4 = [&](int Wo, int Ho) { return dim3((Wo / 4 + 31) / 32, (Ho + 7) / 8, NC); };

    pyrdown4_kernel<<<grid4(640, 640), blk, 0, stream>>>(x,  L1, 1280, 1280, 640, 640, 255.f, 1.f);
    pyrdown4_kernel<<<grid4(320, 320), blk, 0, stream>>>(L1, L2, 640, 640, 320, 320, 1.f, 0.f);
    pyrdown4_kernel<<<grid4(160, 160), blk, 0, stream>>>(L2, L3, 320, 320, 160, 160, 1.f, 0.f);
    pyrdown4_kernel<<<grid4(80,  80),  blk, 0, stream>>>(L3, L4, 160, 160, 80, 80, 1.f, 0.f);
    base_kernel<<<dim3(NC, 1, 1), dim3(256, 1, 1), 0, stream>>>(L4, b30, b150, b300);
    mega_final<<<dim3(20, 20, 8), dim3(256, 1, 1), 0, stream>>>(x, b30, b150, b300, out);
}